// Round 11
// baseline (181.209 us; speedup 1.0000x reference)
//
#include <hip/hip_runtime.h>
#include <stdint.h>

#define HD 512

typedef __bf16 bf16x8 __attribute__((ext_vector_type(8)));
typedef __bf16 bf16x4 __attribute__((ext_vector_type(4)));
typedef float  f32x4  __attribute__((ext_vector_type(4)));

union BF8U { uint4 u; bf16x8 v; };

__device__ __forceinline__ float fast_tanh(float x) {
  x = fminf(15.f, fmaxf(-15.f, x));
  float e = __expf(2.f * x);
  return (e - 1.f) * __builtin_amdgcn_rcpf(e + 1.f);
}
__device__ __forceinline__ float fast_sigmoid(float x) {
  return __builtin_amdgcn_rcpf(1.f + __expf(-x));
}

// ============ setup: prep_w (192 blks) | pool-zero (192 blks) | seg_bounds (160 blks) ====
__global__ void setup_kernel(const float* __restrict__ W0, const float* __restrict__ W1,
                             const float* __restrict__ W2, unsigned short* __restrict__ WbAll,
                             float4* __restrict__ zdst, int nz,
                             const int* __restrict__ seg, int* __restrict__ ss,
                             int* __restrict__ se, int T) {
  int blk = blockIdx.x, t = threadIdx.x;
  if (blk < 192) {
    // ---- W -> bf16 fragment-linear layout
    int mat = blk >> 6, chunk = blk & 63;
    const float* W = (mat == 0) ? W0 : ((mat == 1) ? W1 : W2);
    int np = chunk >> 4, kt = chunk & 15;
    int jl = t & 127, kh = t >> 7;
    int j = np * 128 + jl;
    int nt = jl >> 4;
    unsigned short* base = WbAll + (size_t)mat * 262144 + (size_t)chunk * 4096 + nt * 512;
#pragma unroll
    for (int i = 0; i < 16; ++i) {
      int kk = kh * 16 + i;
      float v = W[(size_t)(kt * 32 + kk) * HD + j];   // coalesced across t
      int l = (kk >> 3) * 16 + (jl & 15);
      int jj = kk & 7;
      union { __bf16 h; unsigned short u; } cv;
      cv.h = (__bf16)v;
      base[l * 8 + jj] = cv.u;
    }
  } else if (blk < 384) {
    // ---- zero the pool accumulators
    int i = (blk - 192) * 256 + t;
    if (i < nz) zdst[i] = make_float4(0.f, 0.f, 0.f, 0.f);
  } else {
    // ---- segment bounds (sorted ids)
    int tt = (blk - 384) * 256 + t;
    if (tt < T) {
      int s = seg[tt];
      if (tt == 0 || seg[tt - 1] != s) ss[s] = tt;
      if (tt == T - 1 || seg[tt + 1] != s) se[s] = tt + 1;
    }
  }
}

// ============ GEMM + tanh + v-dot -> logits (ALL 3 modalities, one dispatch) ============
// R10 structure + FULL 1-ahead B prefetch: loadB(kt+1) issues BEFORE the MFMA
// cluster of kt (and before the barrier -- the memory-clobber asm pins it), so
// B's ~250cyc L2 latency hides under MFMA+ds_read+barrier, same mechanism as
// the proven a4 A-prefetch. Register budget: bf dbuf +16 paid by halving the
// af live range (read 2 A-frags, 8 MFMA, read next 2); launch_bounds caps 128.
__global__ __launch_bounds__(512, 2) void gemm_all_kernel(
    const float* __restrict__ A0, const float* __restrict__ A1, const float* __restrict__ A2,
    const unsigned short* __restrict__ WbAll,
    const float* __restrict__ b0, const float* __restrict__ v0,
    const float* __restrict__ b1, const float* __restrict__ v1,
    const float* __restrict__ b2, const float* __restrict__ v2,
    const int* __restrict__ tokLen, int nTok, int nAst,
    float* __restrict__ lg0, float* __restrict__ lg1, float* __restrict__ lg2)
{
  int bm = blockIdx.x;
  const float* A; const unsigned short* Wb; const float* bias; const float* vvec;
  float* logit; int lb;
  if (bm < nTok) {
    lb = bm; A = A0; Wb = WbAll; bias = b0; vvec = v0; logit = lg0;
    bool i64 = (tokLen[1] == 0);
    int b = lb >> 3;                       // 8 blocks per 512-row batch
    int len = i64 ? tokLen[2 * b] : tokLen[b];
    if (((lb & 7) * 64) >= len) return;    // fully-masked rows: logits never read
  } else if (bm < nTok + nAst) {
    lb = bm - nTok; A = A1; Wb = WbAll + 262144; bias = b1; vvec = v1; logit = lg1;
  } else {
    lb = bm - nTok - nAst; A = A2; Wb = WbAll + 524288; bias = b2; vvec = v2; logit = lg2;
  }
  size_t m0 = (size_t)lb * 64;

  int tid = threadIdx.x, wave = tid >> 6, lane = tid & 63;
  int wn = wave;                                // 8 waves = 8 col-slices of 64

  // A: [2 buf][32 superrows][128 B] (superrow = 2 rows x 32 bf16, swizzled 16B slots)
  __shared__ __align__(16) char AshB[2][4096];
  __shared__ float redS[8][64];                 // epilogue cross-wave reduce

  // ---- A staging: thread t -> row = t>>3, granule q = t&7 (4 f32 = 16B)
  const float* aSrc = A + (m0 + (tid >> 3)) * HD + (tid & 7) * 4;
  const int rowS = tid >> 3, qS = tid & 7;
  const int srW = rowS >> 1;
  const int wA = srW * 128 + 16 * ((((rowS & 1) << 2) + (qS >> 1)) ^ (srW & 7)) + (qS & 1) * 8;

  // ---- B direct-load base: np = wn>>1, half = wn&1 (global col base = wn*64)
  const char* srcB = (const char*)Wb + (size_t)(wn >> 1) * 131072 +
                     (wn & 1) * 4096 + lane * 16;

  // ---- A fragment read addr (row = mt*16 + (lane&15), k0 = (lane>>4)*8)
  const int aRd = ((lane & 15) >> 1) * 128 +
                  16 * ((4 * (lane & 1) + (lane >> 4)) ^ ((lane & 15) >> 1));

  float4 a4;                   // 1-ahead f32 A prefetch
  auto loadA = [&](float4& dst, int kt) {
    dst = *(const float4*)(aSrc + kt * 32);
  };
  auto writeA = [&](int buf, const float4& ar) {
    bf16x4 w0;
    w0[0] = (__bf16)ar.x; w0[1] = (__bf16)ar.y; w0[2] = (__bf16)ar.z; w0[3] = (__bf16)ar.w;
    *(bf16x4*)(&AshB[buf][0] + wA) = w0;
  };
  auto loadB = [&](bf16x8 (&dst)[4], int kt) {
    const char* sB = srcB + (size_t)kt * 8192;
#pragma unroll
    for (int ntl = 0; ntl < 4; ++ntl) {
      BF8U bu;
      bu.u = *(const uint4*)(sB + ntl * 1024);
      dst[ntl] = bu.v;
    }
  };

  f32x4 acc[4][4];
#pragma unroll
  for (int i = 0; i < 4; ++i)
#pragma unroll
    for (int j = 0; j < 4; ++j) acc[i][j] = (f32x4){0.f, 0.f, 0.f, 0.f};

  bf16x8 bfA[4], bfB[4];

  // prologue: A(0) -> LDS buf0; A(1) + B(0) in flight across the barrier
  {
    float4 t4;
    loadA(t4, 0);
    writeA(0, t4);           // compiler inserts counted vmcnt wait on t4 only
    loadA(a4, 1);
    loadB(bfA, 0);
    asm volatile("s_waitcnt lgkmcnt(0)" ::: "memory");
    __builtin_amdgcn_s_barrier();
  }

  auto body = [&](int kt, bf16x8 (&cur)[4], bf16x8 (&nxt)[4]) {
    if (kt < 15) loadB(nxt, kt + 1);       // issued BEFORE MFMAs/barrier: latency hidden
    const char* aBuf = &AshB[kt & 1][0];
    {
      bf16x8 af2[2];
      af2[0] = *(const bf16x8*)(aBuf + 0 * 1024 + aRd);
      af2[1] = *(const bf16x8*)(aBuf + 1 * 1024 + aRd);
#pragma unroll
      for (int mt = 0; mt < 2; ++mt)
#pragma unroll
        for (int ntl = 0; ntl < 4; ++ntl)
          acc[mt][ntl] = __builtin_amdgcn_mfma_f32_16x16x32_bf16(af2[mt], cur[ntl], acc[mt][ntl], 0, 0, 0);
    }
    {
      bf16x8 af2[2];
      af2[0] = *(const bf16x8*)(aBuf + 2 * 1024 + aRd);
      af2[1] = *(const bf16x8*)(aBuf + 3 * 1024 + aRd);
#pragma unroll
      for (int mt = 0; mt < 2; ++mt)
#pragma unroll
        for (int ntl = 0; ntl < 4; ++ntl)
          acc[2 + mt][ntl] = __builtin_amdgcn_mfma_f32_16x16x32_bf16(af2[mt], cur[ntl], acc[2 + mt][ntl], 0, 0, 0);
    }
    if (kt < 15) {
      writeA((kt + 1) & 1, a4);            // consumes data(kt+1), loaded 1 iter ago
      if (kt < 14) loadA(a4, kt + 2);
      asm volatile("s_waitcnt lgkmcnt(0)" ::: "memory");  // publish A ds_writes only
      __builtin_amdgcn_s_barrier();
    }
  };

#pragma unroll
  for (int kt = 0; kt < 16; kt += 2) {
    body(kt, bfA, bfB);
    body(kt + 1, bfB, bfA);
  }

  // ---- epilogue: tanh(acc+b)*v, lane reduce, cross-wave LDS reduce, plain store
  float part[4][4];
#pragma unroll
  for (int mt = 0; mt < 4; ++mt)
#pragma unroll
    for (int i = 0; i < 4; ++i) part[mt][i] = 0.f;

  const int colBase = wn * 64;
#pragma unroll
  for (int ntl = 0; ntl < 4; ++ntl) {
    int j = colBase + ntl * 16 + (lane & 15);
    float bj = bias[j], vj = vvec[j];
#pragma unroll
    for (int mt = 0; mt < 4; ++mt)
#pragma unroll
      for (int i = 0; i < 4; ++i)
        part[mt][i] += fast_tanh(acc[mt][ntl][i] + bj) * vj;
  }
#pragma unroll
  for (int off = 8; off >= 1; off >>= 1)
#pragma unroll
    for (int mt = 0; mt < 4; ++mt)
#pragma unroll
      for (int i = 0; i < 4; ++i)
        part[mt][i] += __shfl_xor(part[mt][i], off, 64);

  if ((lane & 15) == 0) {
    int rloc = (lane >> 4) * 4;
#pragma unroll
    for (int mt = 0; mt < 4; ++mt)
#pragma unroll
      for (int i = 0; i < 4; ++i)
        redS[wn][mt * 16 + rloc + i] = part[mt][i];
  }
  __syncthreads();
  if (tid < 64) {
    float s = 0.f;
#pragma unroll
    for (int w = 0; w < 8; ++w) s += redS[w][tid];
    logit[m0 + tid] = s;
  }
}

// ============ pool: ALL 3 modalities, one dispatch (grid 128 x 10) ============
__global__ void pool_all_kernel(
    const float* __restrict__ tokf, const float* __restrict__ lgT, const int* __restrict__ tl,
    const float* __restrict__ astf, const float* __restrict__ lgA,
    const int* __restrict__ ss, const int* __restrict__ se,
    const float* __restrict__ cfgf, const float* __restrict__ lgC,
    const int* __restrict__ mask, const float* __restrict__ cptr,
    float* __restrict__ pools)
{
  int b = blockIdx.x, chz = blockIdx.y, tid = threadIdx.x;   // 256 threads
  __shared__ float redm[4], reds[4];
  __shared__ float wsh[128];
  int wv = tid >> 6, ln = tid & 63;

  if (chz < 4) {
    // -------- tok: fused masked softmax + pooling --------
    int ch = chz;
    bool i64 = (tl[1] == 0);
    int len = i64 ? tl[2 * b] : tl[b];
    if (ch * 128 >= len) return;
    const float* lg = lgT + b * 512;
    float x0 = (tid < len) ? lg[tid] : -1e30f;
    float x1 = (tid + 256 < len) ? lg[tid + 256] : -1e30f;
    float m = fmaxf(x0, x1);
#pragma unroll
    for (int off = 32; off; off >>= 1) m = fmaxf(m, __shfl_xor(m, off, 64));
    if (ln == 0) redm[wv] = m;
    __syncthreads();
    float bm = fmaxf(fmaxf(redm[0], redm[1]), fmaxf(redm[2], redm[3]));
    float s = ((tid < len) ? __expf(x0 - bm) : 0.f) + ((tid + 256 < len) ? __expf(x1 - bm) : 0.f);
#pragma unroll
    for (int off = 32; off; off >>= 1) s += __shfl_xor(s, off, 64);
    if (ln == 0) reds[wv] = s;
    __syncthreads();
    float bs = reds[0] + reds[1] + reds[2] + reds[3];
    float rb = __builtin_amdgcn_rcpf(bs);
    if (tid < 128) {
      int sidx = ch * 128 + tid;
      wsh[tid] = (sidx < len) ? __expf(lg[sidx] - bm) * rb : 0.f;
    }
    __syncthreads();
    int cnt = min(128, len - ch * 128);
    int h = tid * 2;
    float2 acc = make_float2(0.f, 0.f);
    const float* fb = tokf + ((size_t)b * 512 + ch * 128) * HD + h;
#pragma unroll 4
    for (int s2 = 0; s2 < cnt; ++s2) {
      float2 f = *(const float2*)(fb + (size_t)s2 * HD);
      acc.x += wsh[s2] * f.x; acc.y += wsh[s2] * f.y;
    }
    atomicAdd(&pools[b * 512 + h], acc.x);
    atomicAdd(&pools[b * 512 + h + 1], acc.y);
  } else if (chz < 8) {
    // -------- ast: fused segment softmax + pooling --------
    int ch = chz - 4;
    int t0 = ss[b], t1 = se[b];
    int len = t1 - t0;
    if (len <= 0) return;
    float m = -1e30f;
    for (int t = t0 + tid; t < t1; t += 256) m = fmaxf(m, lgA[t]);
#pragma unroll
    for (int off = 32; off; off >>= 1) m = fmaxf(m, __shfl_xor(m, off, 64));
    if (ln == 0) redm[wv] = m;
    __syncthreads();
    float bm = fmaxf(fmaxf(redm[0], redm[1]), fmaxf(redm[2], redm[3]));
    float s = 0.f;
    for (int t = t0 + tid; t < t1; t += 256) s += __expf(lgA[t] - bm);
#pragma unroll
    for (int off = 32; off; off >>= 1) s += __shfl_xor(s, off, 64);
    if (ln == 0) reds[wv] = s;
    __syncthreads();
    float bs = reds[0] + reds[1] + reds[2] + reds[3];
    float r = __builtin_amdgcn_rcpf(bs);
    int per = (len + 3) >> 2;
    int a0 = t0 + ch * per;
    int a1 = min(t1, a0 + per);
    int h = tid * 2;
    float2 acc = make_float2(0.f, 0.f);
    for (int base = a0; base < a1; base += 128) {
      int cnt = min(128, a1 - base);
      __syncthreads();
      if (tid < cnt) wsh[tid] = __expf(lgA[base + tid] - bm) * r;
      __syncthreads();
      for (int s2 = 0; s2 < cnt; ++s2) {
        float2 f = *(const float2*)(astf + (size_t)(base + s2) * HD + h);
        acc.x += wsh[s2] * f.x; acc.y += wsh[s2] * f.y;
      }
    }
    atomicAdd(&pools[65536 + b * 512 + h], acc.x);
    atomicAdd(&pools[65536 + b * 512 + h + 1], acc.y);
  } else {
    // -------- cfg: sigmoid-gated pooling --------
    int ch = chz - 8;
    float cc = cptr[0];
    int n0 = ch * 128;
    if (tid < 128) {
      int n = n0 + tid;
      float g = fast_sigmoid(lgC[b * 256 + n] + cc);
      wsh[tid] = mask[b * 256 + n] ? g : 0.f;
    }
    __syncthreads();
    int h = tid * 2;
    float2 acc = make_float2(0.f, 0.f);
    const float* fb = cfgf + ((size_t)b * 256 + n0) * HD + h;
#pragma unroll 4
    for (int s2 = 0; s2 < 128; ++s2) {
      float2 f = *(const float2*)(fb + (size_t)s2 * HD);
      acc.x += wsh[s2] * f.x; acc.y += wsh[s2] * f.y;
    }
    atomicAdd(&pools[131072 + b * 512 + h], acc.x);
    atomicAdd(&pools[131072 + b * 512 + h + 1], acc.y);
  }
}

// ============ fusion: concat @ W_fuse, no atomics ============
__global__ void fuse_partial_kernel(const float* __restrict__ pools,   // [3][128][512]
                                    const float* __restrict__ Wf,
                                    float* __restrict__ fpart) {       // [12][128][512]
  int bg = blockIdx.x, kc = blockIdx.y;
  int tid = threadIdx.x;
  int bq = tid >> 7, jt = tid & 127;
  __shared__ float psh[8][128];
  for (int idx = tid; idx < 8 * 128; idx += 256) {
    int bb = idx >> 7, kk = idx & 127;
    int i = kc * 128 + kk;
    psh[bb][kk] = pools[(size_t)(i >> 9) * 65536 + (size_t)(bg * 8 + bb) * 512 + (i & 511)];
  }
  __syncthreads();
  f32x4 acc[4];
#pragma unroll
  for (int bb = 0; bb < 4; ++bb) acc[bb] = (f32x4){0.f, 0.f, 0.f, 0.f};
  const float* wrow = Wf + (size_t)(kc * 128) * 512 + jt * 4;
#pragma unroll 4
  for (int k = 0; k < 128; ++k) {
    float4 wv = *(const float4*)(wrow + (size_t)k * 512);
#pragma unroll
    for (int bb = 0; bb < 4; ++bb) {
      float p = psh[bq * 4 + bb][k];
      acc[bb][0] += p * wv.x; acc[bb][1] += p * wv.y;
      acc[bb][2] += p * wv.z; acc[bb][3] += p * wv.w;
    }
  }
  float* dst = fpart + (size_t)kc * 65536 + (size_t)(bg * 8 + bq * 4) * 512 + jt * 4;
#pragma unroll
  for (int bb = 0; bb < 4; ++bb)
    *(f32x4*)(dst + (size_t)bb * 512) = acc[bb];
}

__global__ void finalize_kernel(const float* __restrict__ fpart, const float* __restrict__ bfuse,
                                float* __restrict__ out) {
  int idx = blockIdx.x * 256 + threadIdx.x;  // 65536
  float s = bfuse[idx & 511];
#pragma unroll
  for (int kc = 0; kc < 12; ++kc) s += fpart[(size_t)kc * 65536 + idx];
  out[idx] = fast_tanh(s);
}

// ============ workspace layout (bytes) ============
static constexpr size_t OFF_WB_ALL = 0;                              // 3 * 512KB
static constexpr size_t OFF_LG_TOK = 1536 * 1024;                    // 65536 f32 (no zero)
static constexpr size_t OFF_LG_AST = OFF_LG_TOK + 65536 * 4;         // 40960 f32
static constexpr size_t OFF_LG_CFG = OFF_LG_AST + 40960 * 4;         // 32768 f32
static constexpr size_t OFF_POOLS  = OFF_LG_CFG + 32768 * 4;         // 3*65536 f32 (zeroed)
static constexpr size_t OFF_SS     = OFF_POOLS + 3 * 65536 * 4;      // 128 i32 (written fully)
static constexpr size_t OFF_SE     = OFF_SS + 512;
static constexpr size_t OFF_FPART  = OFF_SE + 512;                   // 12*65536 f32
static constexpr int    ZERO_N4    = (3 * 65536 * 4) / 16;           // pools only

extern "C" void kernel_launch(void* const* d_in, const int* in_sizes, int n_in,
                              void* d_out, int out_size, void* d_ws, size_t ws_size,
                              hipStream_t stream) {
  const float* tok_feat = (const float*)d_in[0];
  const float* ast_h    = (const float*)d_in[1];
  const float* cfg_feat = (const float*)d_in[2];
  const float* W_tok = (const float*)d_in[3];
  const float* b_tok = (const float*)d_in[4];
  const float* v_tok = (const float*)d_in[5];
  const float* W_ast = (const float*)d_in[7];
  const float* b_ast = (const float*)d_in[8];
  const float* v_ast = (const float*)d_in[9];
  const float* W_cfg = (const float*)d_in[11];
  const float* b_cfg = (const float*)d_in[12];
  const float* v_cfg = (const float*)d_in[13];
  const float* c_cfg = (const float*)d_in[14];
  const float* W_fuse = (const float*)d_in[15];
  const float* b_fuse = (const float*)d_in[16];
  const int* tok_len  = (const int*)d_in[17];
  const int* node_seg = (const int*)d_in[18];
  const int* cfg_mask = (const int*)d_in[19];

  const int M_tok = in_sizes[0] / HD;   // 65536
  const int T_ast = in_sizes[1] / HD;   // 40960
  const int M_cfg = in_sizes[2] / HD;   // 32768
  const int nTok = M_tok / 64, nAst = T_ast / 64, nCfg = M_cfg / 64;

  char* ws = (char*)d_ws;
  unsigned short* wbAll = (unsigned short*)(ws + OFF_WB_ALL);
  float* lgTok = (float*)(ws + OFF_LG_TOK);
  float* lgAst = (float*)(ws + OFF_LG_AST);
  float* lgCfg = (float*)(ws + OFF_LG_CFG);
  float* pools = (float*)(ws + OFF_POOLS);
  int*   ss    = (int*)(ws + OFF_SS);
  int*   se    = (int*)(ws + OFF_SE);
  float* fpart = (float*)(ws + OFF_FPART);

  // ---- setup: prep_w | zero pools | seg_bounds (one dispatch)
  int segBlks = (T_ast + 255) / 256;
  setup_kernel<<<384 + segBlks, 256, 0, stream>>>(
      W_tok, W_ast, W_cfg, wbAll, (float4*)(ws + OFF_POOLS), ZERO_N4,
      node_seg, ss, se, T_ast);

  // ---- all three gemms, one dispatch
  gemm_all_kernel<<<nTok + nAst + nCfg, 512, 0, stream>>>(
      tok_feat, ast_h, cfg_feat, wbAll,
      b_tok, v_tok, b_ast, v_ast, b_cfg, v_cfg,
      tok_len, nTok, nAst, lgTok, lgAst, lgCfg);

  // ---- all three pools, one dispatch
  pool_all_kernel<<<dim3(128, 10), 256, 0, stream>>>(
      tok_feat, lgTok, tok_len,
      ast_h, lgAst, ss, se,
      cfg_feat, lgCfg, cfg_mask, c_cfg, pools);

  // ---- fusion
  fuse_partial_kernel<<<dim3(16, 12), 256, 0, stream>>>(pools, W_fuse, fpart);
  finalize_kernel<<<256, 256, 0, stream>>>(fpart, b_fuse, (float*)d_out);
}

// Round 12
// 157.751 us; speedup vs baseline: 1.1487x; 1.1487x over previous
//
#include <hip/hip_runtime.h>
#include <stdint.h>

#define HD 512

typedef __bf16 bf16x8 __attribute__((ext_vector_type(8)));
typedef __bf16 bf16x4 __attribute__((ext_vector_type(4)));
typedef float  f32x4  __attribute__((ext_vector_type(4)));

union BF8U { uint4 u; bf16x8 v; };

__device__ __forceinline__ float fast_tanh(float x) {
  x = fminf(15.f, fmaxf(-15.f, x));
  float e = __expf(2.f * x);
  return (e - 1.f) * __builtin_amdgcn_rcpf(e + 1.f);
}
__device__ __forceinline__ float fast_sigmoid(float x) {
  return __builtin_amdgcn_rcpf(1.f + __expf(-x));
}

// ============ setup: prep_w (192 blks) | pool-zero (192 blks) | seg_bounds (160 blks) ====
__global__ void setup_kernel(const float* __restrict__ W0, const float* __restrict__ W1,
                             const float* __restrict__ W2, unsigned short* __restrict__ WbAll,
                             float4* __restrict__ zdst, int nz,
                             const int* __restrict__ seg, int* __restrict__ ss,
                             int* __restrict__ se, int T) {
  int blk = blockIdx.x, t = threadIdx.x;
  if (blk < 192) {
    // ---- W -> bf16 fragment-linear layout
    int mat = blk >> 6, chunk = blk & 63;
    const float* W = (mat == 0) ? W0 : ((mat == 1) ? W1 : W2);
    int np = chunk >> 4, kt = chunk & 15;
    int jl = t & 127, kh = t >> 7;
    int j = np * 128 + jl;
    int nt = jl >> 4;
    unsigned short* base = WbAll + (size_t)mat * 262144 + (size_t)chunk * 4096 + nt * 512;
#pragma unroll
    for (int i = 0; i < 16; ++i) {
      int kk = kh * 16 + i;
      float v = W[(size_t)(kt * 32 + kk) * HD + j];   // coalesced across t
      int l = (kk >> 3) * 16 + (jl & 15);
      int jj = kk & 7;
      union { __bf16 h; unsigned short u; } cv;
      cv.h = (__bf16)v;
      base[l * 8 + jj] = cv.u;
    }
  } else if (blk < 384) {
    // ---- zero the pool accumulators
    int i = (blk - 192) * 256 + t;
    if (i < nz) zdst[i] = make_float4(0.f, 0.f, 0.f, 0.f);
  } else {
    // ---- segment bounds (sorted ids)
    int tt = (blk - 384) * 256 + t;
    if (tt < T) {
      int s = seg[tt];
      if (tt == 0 || seg[tt - 1] != s) ss[s] = tt;
      if (tt == T - 1 || seg[tt + 1] != s) se[s] = tt + 1;
    }
  }
}

// ============ GEMM + tanh + v-dot -> logits (ALL 3 modalities, one dispatch) ============
// R11 structure (full 1-ahead B prefetch -- proven 1.6x per-block efficiency) with
// __launch_bounds__(512,4): forces total regs (VGPR+acc) <= 128 so TWO blocks stay
// resident per CU. R11's only failure was (512,2) allowing 132 regs -> 1 block/CU.
__global__ __launch_bounds__(512, 4) void gemm_all_kernel(
    const float* __restrict__ A0, const float* __restrict__ A1, const float* __restrict__ A2,
    const unsigned short* __restrict__ WbAll,
    const float* __restrict__ b0, const float* __restrict__ v0,
    const float* __restrict__ b1, const float* __restrict__ v1,
    const float* __restrict__ b2, const float* __restrict__ v2,
    const int* __restrict__ tokLen, int nTok, int nAst,
    float* __restrict__ lg0, float* __restrict__ lg1, float* __restrict__ lg2)
{
  int bm = blockIdx.x;
  const float* A; const unsigned short* Wb; const float* bias; const float* vvec;
  float* logit; int lb;
  if (bm < nTok) {
    lb = bm; A = A0; Wb = WbAll; bias = b0; vvec = v0; logit = lg0;
    bool i64 = (tokLen[1] == 0);
    int b = lb >> 3;                       // 8 blocks per 512-row batch
    int len = i64 ? tokLen[2 * b] : tokLen[b];
    if (((lb & 7) * 64) >= len) return;    // fully-masked rows: logits never read
  } else if (bm < nTok + nAst) {
    lb = bm - nTok; A = A1; Wb = WbAll + 262144; bias = b1; vvec = v1; logit = lg1;
  } else {
    lb = bm - nTok - nAst; A = A2; Wb = WbAll + 524288; bias = b2; vvec = v2; logit = lg2;
  }
  size_t m0 = (size_t)lb * 64;

  int tid = threadIdx.x, wave = tid >> 6, lane = tid & 63;
  int wn = wave;                                // 8 waves = 8 col-slices of 64

  // A: [2 buf][32 superrows][128 B] (superrow = 2 rows x 32 bf16, swizzled 16B slots)
  __shared__ __align__(16) char AshB[2][4096];
  __shared__ float redS[8][64];                 // epilogue cross-wave reduce

  // ---- A staging: thread t -> row = t>>3, granule q = t&7 (4 f32 = 16B)
  const float* aSrc = A + (m0 + (tid >> 3)) * HD + (tid & 7) * 4;
  const int rowS = tid >> 3, qS = tid & 7;
  const int srW = rowS >> 1;
  const int wA = srW * 128 + 16 * ((((rowS & 1) << 2) + (qS >> 1)) ^ (srW & 7)) + (qS & 1) * 8;

  // ---- B direct-load base: np = wn>>1, half = wn&1 (global col base = wn*64)
  const char* srcB = (const char*)Wb + (size_t)(wn >> 1) * 131072 +
                     (wn & 1) * 4096 + lane * 16;

  // ---- A fragment read addr (row = mt*16 + (lane&15), k0 = (lane>>4)*8)
  const int aRd = ((lane & 15) >> 1) * 128 +
                  16 * ((4 * (lane & 1) + (lane >> 4)) ^ ((lane & 15) >> 1));

  float4 a4;                   // 1-ahead f32 A prefetch
  auto loadA = [&](float4& dst, int kt) {
    dst = *(const float4*)(aSrc + kt * 32);
  };
  auto writeA = [&](int buf, const float4& ar) {
    bf16x4 w0;
    w0[0] = (__bf16)ar.x; w0[1] = (__bf16)ar.y; w0[2] = (__bf16)ar.z; w0[3] = (__bf16)ar.w;
    *(bf16x4*)(&AshB[buf][0] + wA) = w0;
  };
  auto loadB = [&](bf16x8 (&dst)[4], int kt) {
    const char* sB = srcB + (size_t)kt * 8192;
#pragma unroll
    for (int ntl = 0; ntl < 4; ++ntl) {
      BF8U bu;
      bu.u = *(const uint4*)(sB + ntl * 1024);
      dst[ntl] = bu.v;
    }
  };

  f32x4 acc[4][4];
#pragma unroll
  for (int i = 0; i < 4; ++i)
#pragma unroll
    for (int j = 0; j < 4; ++j) acc[i][j] = (f32x4){0.f, 0.f, 0.f, 0.f};

  bf16x8 bfA[4], bfB[4];

  // prologue: A(0) -> LDS buf0; A(1) + B(0) in flight across the barrier
  {
    float4 t4;
    loadA(t4, 0);
    writeA(0, t4);           // compiler inserts counted vmcnt wait on t4 only
    loadA(a4, 1);
    loadB(bfA, 0);
    asm volatile("s_waitcnt lgkmcnt(0)" ::: "memory");
    __builtin_amdgcn_s_barrier();
  }

  auto body = [&](int kt, bf16x8 (&cur)[4], bf16x8 (&nxt)[4]) {
    if (kt < 15) loadB(nxt, kt + 1);       // issued BEFORE MFMAs/barrier: latency hidden
    const char* aBuf = &AshB[kt & 1][0];
    {
      bf16x8 af2[2];
      af2[0] = *(const bf16x8*)(aBuf + 0 * 1024 + aRd);
      af2[1] = *(const bf16x8*)(aBuf + 1 * 1024 + aRd);
#pragma unroll
      for (int mt = 0; mt < 2; ++mt)
#pragma unroll
        for (int ntl = 0; ntl < 4; ++ntl)
          acc[mt][ntl] = __builtin_amdgcn_mfma_f32_16x16x32_bf16(af2[mt], cur[ntl], acc[mt][ntl], 0, 0, 0);
    }
    {
      bf16x8 af2[2];
      af2[0] = *(const bf16x8*)(aBuf + 2 * 1024 + aRd);
      af2[1] = *(const bf16x8*)(aBuf + 3 * 1024 + aRd);
#pragma unroll
      for (int mt = 0; mt < 2; ++mt)
#pragma unroll
        for (int ntl = 0; ntl < 4; ++ntl)
          acc[2 + mt][ntl] = __builtin_amdgcn_mfma_f32_16x16x32_bf16(af2[mt], cur[ntl], acc[2 + mt][ntl], 0, 0, 0);
    }
    if (kt < 15) {
      writeA((kt + 1) & 1, a4);            // consumes data(kt+1), loaded 1 iter ago
      if (kt < 14) loadA(a4, kt + 2);
      asm volatile("s_waitcnt lgkmcnt(0)" ::: "memory");  // publish A ds_writes only
      __builtin_amdgcn_s_barrier();
    }
  };

#pragma unroll
  for (int kt = 0; kt < 16; kt += 2) {
    body(kt, bfA, bfB);
    body(kt + 1, bfB, bfA);
  }

  // ---- epilogue: tanh(acc+b)*v, lane reduce, cross-wave LDS reduce, plain store
  float part[4][4];
#pragma unroll
  for (int mt = 0; mt < 4; ++mt)
#pragma unroll
    for (int i = 0; i < 4; ++i) part[mt][i] = 0.f;

  const int colBase = wn * 64;
#pragma unroll
  for (int ntl = 0; ntl < 4; ++ntl) {
    int j = colBase + ntl * 16 + (lane & 15);
    float bj = bias[j], vj = vvec[j];
#pragma unroll
    for (int mt = 0; mt < 4; ++mt)
#pragma unroll
      for (int i = 0; i < 4; ++i)
        part[mt][i] += fast_tanh(acc[mt][ntl][i] + bj) * vj;
  }
#pragma unroll
  for (int off = 8; off >= 1; off >>= 1)
#pragma unroll
    for (int mt = 0; mt < 4; ++mt)
#pragma unroll
      for (int i = 0; i < 4; ++i)
        part[mt][i] += __shfl_xor(part[mt][i], off, 64);

  if ((lane & 15) == 0) {
    int rloc = (lane >> 4) * 4;
#pragma unroll
    for (int mt = 0; mt < 4; ++mt)
#pragma unroll
      for (int i = 0; i < 4; ++i)
        redS[wn][mt * 16 + rloc + i] = part[mt][i];
  }
  __syncthreads();
  if (tid < 64) {
    float s = 0.f;
#pragma unroll
    for (int w = 0; w < 8; ++w) s += redS[w][tid];
    logit[m0 + tid] = s;
  }
}

// ============ pool: ALL 3 modalities, one dispatch (grid 128 x 10) ============
__global__ void pool_all_kernel(
    const float* __restrict__ tokf, const float* __restrict__ lgT, const int* __restrict__ tl,
    const float* __restrict__ astf, const float* __restrict__ lgA,
    const int* __restrict__ ss, const int* __restrict__ se,
    const float* __restrict__ cfgf, const float* __restrict__ lgC,
    const int* __restrict__ mask, const float* __restrict__ cptr,
    float* __restrict__ pools)
{
  int b = blockIdx.x, chz = blockIdx.y, tid = threadIdx.x;   // 256 threads
  __shared__ float redm[4], reds[4];
  __shared__ float wsh[128];
  int wv = tid >> 6, ln = tid & 63;

  if (chz < 4) {
    // -------- tok: fused masked softmax + pooling --------
    int ch = chz;
    bool i64 = (tl[1] == 0);
    int len = i64 ? tl[2 * b] : tl[b];
    if (ch * 128 >= len) return;
    const float* lg = lgT + b * 512;
    float x0 = (tid < len) ? lg[tid] : -1e30f;
    float x1 = (tid + 256 < len) ? lg[tid + 256] : -1e30f;
    float m = fmaxf(x0, x1);
#pragma unroll
    for (int off = 32; off; off >>= 1) m = fmaxf(m, __shfl_xor(m, off, 64));
    if (ln == 0) redm[wv] = m;
    __syncthreads();
    float bm = fmaxf(fmaxf(redm[0], redm[1]), fmaxf(redm[2], redm[3]));
    float s = ((tid < len) ? __expf(x0 - bm) : 0.f) + ((tid + 256 < len) ? __expf(x1 - bm) : 0.f);
#pragma unroll
    for (int off = 32; off; off >>= 1) s += __shfl_xor(s, off, 64);
    if (ln == 0) reds[wv] = s;
    __syncthreads();
    float bs = reds[0] + reds[1] + reds[2] + reds[3];
    float rb = __builtin_amdgcn_rcpf(bs);
    if (tid < 128) {
      int sidx = ch * 128 + tid;
      wsh[tid] = (sidx < len) ? __expf(lg[sidx] - bm) * rb : 0.f;
    }
    __syncthreads();
    int cnt = min(128, len - ch * 128);
    int h = tid * 2;
    float2 acc = make_float2(0.f, 0.f);
    const float* fb = tokf + ((size_t)b * 512 + ch * 128) * HD + h;
#pragma unroll 4
    for (int s2 = 0; s2 < cnt; ++s2) {
      float2 f = *(const float2*)(fb + (size_t)s2 * HD);
      acc.x += wsh[s2] * f.x; acc.y += wsh[s2] * f.y;
    }
    atomicAdd(&pools[b * 512 + h], acc.x);
    atomicAdd(&pools[b * 512 + h + 1], acc.y);
  } else if (chz < 8) {
    // -------- ast: fused segment softmax + pooling --------
    int ch = chz - 4;
    int t0 = ss[b], t1 = se[b];
    int len = t1 - t0;
    if (len <= 0) return;
    float m = -1e30f;
    for (int t = t0 + tid; t < t1; t += 256) m = fmaxf(m, lgA[t]);
#pragma unroll
    for (int off = 32; off; off >>= 1) m = fmaxf(m, __shfl_xor(m, off, 64));
    if (ln == 0) redm[wv] = m;
    __syncthreads();
    float bm = fmaxf(fmaxf(redm[0], redm[1]), fmaxf(redm[2], redm[3]));
    float s = 0.f;
    for (int t = t0 + tid; t < t1; t += 256) s += __expf(lgA[t] - bm);
#pragma unroll
    for (int off = 32; off; off >>= 1) s += __shfl_xor(s, off, 64);
    if (ln == 0) reds[wv] = s;
    __syncthreads();
    float bs = reds[0] + reds[1] + reds[2] + reds[3];
    float r = __builtin_amdgcn_rcpf(bs);
    int per = (len + 3) >> 2;
    int a0 = t0 + ch * per;
    int a1 = min(t1, a0 + per);
    int h = tid * 2;
    float2 acc = make_float2(0.f, 0.f);
    for (int base = a0; base < a1; base += 128) {
      int cnt = min(128, a1 - base);
      __syncthreads();
      if (tid < cnt) wsh[tid] = __expf(lgA[base + tid] - bm) * r;
      __syncthreads();
      for (int s2 = 0; s2 < cnt; ++s2) {
        float2 f = *(const float2*)(astf + (size_t)(base + s2) * HD + h);
        acc.x += wsh[s2] * f.x; acc.y += wsh[s2] * f.y;
      }
    }
    atomicAdd(&pools[65536 + b * 512 + h], acc.x);
    atomicAdd(&pools[65536 + b * 512 + h + 1], acc.y);
  } else {
    // -------- cfg: sigmoid-gated pooling --------
    int ch = chz - 8;
    float cc = cptr[0];
    int n0 = ch * 128;
    if (tid < 128) {
      int n = n0 + tid;
      float g = fast_sigmoid(lgC[b * 256 + n] + cc);
      wsh[tid] = mask[b * 256 + n] ? g : 0.f;
    }
    __syncthreads();
    int h = tid * 2;
    float2 acc = make_float2(0.f, 0.f);
    const float* fb = cfgf + ((size_t)b * 256 + n0) * HD + h;
#pragma unroll 4
    for (int s2 = 0; s2 < 128; ++s2) {
      float2 f = *(const float2*)(fb + (size_t)s2 * HD);
      acc.x += wsh[s2] * f.x; acc.y += wsh[s2] * f.y;
    }
    atomicAdd(&pools[131072 + b * 512 + h], acc.x);
    atomicAdd(&pools[131072 + b * 512 + h + 1], acc.y);
  }
}

// ============ fusion: concat @ W_fuse, no atomics ============
__global__ void fuse_partial_kernel(const float* __restrict__ pools,   // [3][128][512]
                                    const float* __restrict__ Wf,
                                    float* __restrict__ fpart) {       // [12][128][512]
  int bg = blockIdx.x, kc = blockIdx.y;
  int tid = threadIdx.x;
  int bq = tid >> 7, jt = tid & 127;
  __shared__ float psh[8][128];
  for (int idx = tid; idx < 8 * 128; idx += 256) {
    int bb = idx >> 7, kk = idx & 127;
    int i = kc * 128 + kk;
    psh[bb][kk] = pools[(size_t)(i >> 9) * 65536 + (size_t)(bg * 8 + bb) * 512 + (i & 511)];
  }
  __syncthreads();
  f32x4 acc[4];
#pragma unroll
  for (int bb = 0; bb < 4; ++bb) acc[bb] = (f32x4){0.f, 0.f, 0.f, 0.f};
  const float* wrow = Wf + (size_t)(kc * 128) * 512 + jt * 4;
#pragma unroll 4
  for (int k = 0; k < 128; ++k) {
    float4 wv = *(const float4*)(wrow + (size_t)k * 512);
#pragma unroll
    for (int bb = 0; bb < 4; ++bb) {
      float p = psh[bq * 4 + bb][k];
      acc[bb][0] += p * wv.x; acc[bb][1] += p * wv.y;
      acc[bb][2] += p * wv.z; acc[bb][3] += p * wv.w;
    }
  }
  float* dst = fpart + (size_t)kc * 65536 + (size_t)(bg * 8 + bq * 4) * 512 + jt * 4;
#pragma unroll
  for (int bb = 0; bb < 4; ++bb)
    *(f32x4*)(dst + (size_t)bb * 512) = acc[bb];
}

__global__ void finalize_kernel(const float* __restrict__ fpart, const float* __restrict__ bfuse,
                                float* __restrict__ out) {
  int idx = blockIdx.x * 256 + threadIdx.x;  // 65536
  float s = bfuse[idx & 511];
#pragma unroll
  for (int kc = 0; kc < 12; ++kc) s += fpart[(size_t)kc * 65536 + idx];
  out[idx] = fast_tanh(s);
}

// ============ workspace layout (bytes) ============
static constexpr size_t OFF_WB_ALL = 0;                              // 3 * 512KB
static constexpr size_t OFF_LG_TOK = 1536 * 1024;                    // 65536 f32 (no zero)
static constexpr size_t OFF_LG_AST = OFF_LG_TOK + 65536 * 4;         // 40960 f32
static constexpr size_t OFF_LG_CFG = OFF_LG_AST + 40960 * 4;         // 32768 f32
static constexpr size_t OFF_POOLS  = OFF_LG_CFG + 32768 * 4;         // 3*65536 f32 (zeroed)
static constexpr size_t OFF_SS     = OFF_POOLS + 3 * 65536 * 4;      // 128 i32 (written fully)
static constexpr size_t OFF_SE     = OFF_SS + 512;
static constexpr size_t OFF_FPART  = OFF_SE + 512;                   // 12*65536 f32
static constexpr int    ZERO_N4    = (3 * 65536 * 4) / 16;           // pools only

extern "C" void kernel_launch(void* const* d_in, const int* in_sizes, int n_in,
                              void* d_out, int out_size, void* d_ws, size_t ws_size,
                              hipStream_t stream) {
  const float* tok_feat = (const float*)d_in[0];
  const float* ast_h    = (const float*)d_in[1];
  const float* cfg_feat = (const float*)d_in[2];
  const float* W_tok = (const float*)d_in[3];
  const float* b_tok = (const float*)d_in[4];
  const float* v_tok = (const float*)d_in[5];
  const float* W_ast = (const float*)d_in[7];
  const float* b_ast = (const float*)d_in[8];
  const float* v_ast = (const float*)d_in[9];
  const float* W_cfg = (const float*)d_in[11];
  const float* b_cfg = (const float*)d_in[12];
  const float* v_cfg = (const float*)d_in[13];
  const float* c_cfg = (const float*)d_in[14];
  const float* W_fuse = (const float*)d_in[15];
  const float* b_fuse = (const float*)d_in[16];
  const int* tok_len  = (const int*)d_in[17];
  const int* node_seg = (const int*)d_in[18];
  const int* cfg_mask = (const int*)d_in[19];

  const int M_tok = in_sizes[0] / HD;   // 65536
  const int T_ast = in_sizes[1] / HD;   // 40960
  const int M_cfg = in_sizes[2] / HD;   // 32768
  const int nTok = M_tok / 64, nAst = T_ast / 64, nCfg = M_cfg / 64;

  char* ws = (char*)d_ws;
  unsigned short* wbAll = (unsigned short*)(ws + OFF_WB_ALL);
  float* lgTok = (float*)(ws + OFF_LG_TOK);
  float* lgAst = (float*)(ws + OFF_LG_AST);
  float* lgCfg = (float*)(ws + OFF_LG_CFG);
  float* pools = (float*)(ws + OFF_POOLS);
  int*   ss    = (int*)(ws + OFF_SS);
  int*   se    = (int*)(ws + OFF_SE);
  float* fpart = (float*)(ws + OFF_FPART);

  // ---- setup: prep_w | zero pools | seg_bounds (one dispatch)
  int segBlks = (T_ast + 255) / 256;
  setup_kernel<<<384 + segBlks, 256, 0, stream>>>(
      W_tok, W_ast, W_cfg, wbAll, (float4*)(ws + OFF_POOLS), ZERO_N4,
      node_seg, ss, se, T_ast);

  // ---- all three gemms, one dispatch
  gemm_all_kernel<<<nTok + nAst + nCfg, 512, 0, stream>>>(
      tok_feat, ast_h, cfg_feat, wbAll,
      b_tok, v_tok, b_ast, v_ast, b_cfg, v_cfg,
      tok_len, nTok, nAst, lgTok, lgAst, lgCfg);

  // ---- all three pools, one dispatch
  pool_all_kernel<<<dim3(128, 10), 256, 0, stream>>>(
      tok_feat, lgTok, tok_len,
      ast_h, lgAst, ss, se,
      cfg_feat, lgCfg, cfg_mask, c_cfg, pools);

  // ---- fusion
  fuse_partial_kernel<<<dim3(16, 12), 256, 0, stream>>>(pools, W_fuse, fpart);
  finalize_kernel<<<256, 256, 0, stream>>>(fpart, b_fuse, (float*)d_out);
}